// Round 1
// 163.952 us; speedup vs baseline: 1.0851x; 1.0851x over previous
//
#include <hip/hip_runtime.h>

typedef unsigned short u16;
typedef unsigned int u32;
typedef __attribute__((ext_vector_type(8))) short bf16x8;
typedef __attribute__((ext_vector_type(4))) float f32x4;

__device__ __forceinline__ u16 f2bf(float x) {
  unsigned u = __float_as_uint(x);
  u += 0x7fffu + ((u >> 16) & 1u);   // RNE
  return (u16)(u >> 16);
}
__device__ __forceinline__ float bf2f(u16 z) {
  return __uint_as_float((u32)z << 16);
}

// ---- cast fp32 -> bf16 (RNE); n divisible by 1024. Also builds rope table ----
// rtab[t*16+i] = {cos(t*fr_i), sin(t*fr_i)}, fr_i = 1024^(-i/15), t<2048, i<16.
__global__ __launch_bounds__(256) void cast_kernel(const float* __restrict__ in,
                                                   u16* __restrict__ out, int n,
                                                   float2* __restrict__ rtab) {
  int g = blockIdx.x * 256 + threadIdx.x;
  int i = g * 4;
  if (i < n) {
    float4 f = *(const float4*)(in + i);
    ushort4 o;
    o.x = f2bf(f.x); o.y = f2bf(f.y); o.z = f2bf(f.z); o.w = f2bf(f.w);
    *(ushort4*)(out + i) = o;
  }
  if (g < 2048 * 16) {
    int t = g >> 4, ii = g & 15;
    float fr = exp2f(-10.0f * (float)ii / 15.0f);
    float th = (float)t * fr;
    rtab[g] = make_float2(cosf(th), sinf(th));
  }
}

// ------------- transpose+cast 4 weights: W[k][n] fp32 -> Wt[n][k] bf16 -------------
__global__ __launch_bounds__(256) void transcast(const float* __restrict__ W0,
                                                 const float* __restrict__ W1,
                                                 const float* __restrict__ W2,
                                                 const float* __restrict__ W3,
                                                 u16* __restrict__ out) {
  __shared__ alignas(16) u16 ls[64 * 72];
  int z = blockIdx.z;
  const float* W = (z == 0) ? W0 : (z == 1) ? W1 : (z == 2) ? W2 : W3;
  u16* o = out + (size_t)z * (1024u * 1024u);
  int kt = blockIdx.y * 64, nt = blockIdx.x * 64;
  int tid = threadIdx.x;
  int r = tid >> 2, c0 = (tid & 3) * 16;
  const float* src = W + (size_t)(kt + r) * 1024 + nt + c0;
  u16 tmp[16];
#pragma unroll
  for (int c = 0; c < 16; c += 4) {
    float4 f = *(const float4*)(src + c);
    tmp[c + 0] = f2bf(f.x); tmp[c + 1] = f2bf(f.y);
    tmp[c + 2] = f2bf(f.z); tmp[c + 3] = f2bf(f.w);
  }
#pragma unroll
  for (int c = 0; c < 16; ++c) ls[r * 72 + c0 + c] = tmp[c];
  __syncthreads();
#pragma unroll
  for (int pass = 0; pass < 4; ++pass) {
    int n = pass * 16 + (tid >> 4);
    int kk = (tid & 15) * 4;
    ushort4 val;
    val.x = ls[(kk + 0) * 72 + n];
    val.y = ls[(kk + 1) * 72 + n];
    val.z = ls[(kk + 2) * 72 + n];
    val.w = ls[(kk + 3) * 72 + n];
    *(ushort4*)(o + (size_t)(nt + n) * 1024 + kt + kk) = val;
  }
}

#define GLD 40  // LDS stride: rows alias at +8 -> 2-way on banks (free)

// ---- fused QKV GEMM 128x128, full K=1024, epilogue norm+rope (q,k) / transpose (v) ----
// grid (8 n-tiles, 16 m-tiles, z=3 projections). A wave's 64 cols = one full head,
// so cosine-norm (shfl over m16 + sum over nt) and rotary (nt <-> nt^2 pairing)
// are wave/register-local. V is written transposed via per-lane ushort4 (r = t run).
__global__ __launch_bounds__(256) void gemm_qkv(const u16* __restrict__ A,
                                                const u16* __restrict__ Wt,
                                                u16* __restrict__ qb,
                                                u16* __restrict__ kb,
                                                u16* __restrict__ vt,
                                                const float* __restrict__ s_qk,
                                                const float2* __restrict__ rtab) {
  __shared__ alignas(16) u16 As[128 * GLD];
  __shared__ alignas(16) u16 Bs[128 * GLD];
  int z = blockIdx.z;
  const u16* B = Wt + (size_t)z * (1024u * 1024u);
  int tid = threadIdx.x;
  int bm = blockIdx.y * 128, bn = blockIdx.x * 128;
  int lane = tid & 63, w = tid >> 6;
  int wm = (w >> 1) * 64, wn = (w & 1) * 64;
  int m16 = lane & 15, q = lane >> 4;
  f32x4 acc[4][4] = {};
  int srow = tid >> 1, scol = (tid & 1) * 16;
  const u16* aptr = A + (size_t)(bm + srow) * 1024 + scol;
  const u16* bptr = B + (size_t)(bn + srow) * 1024 + scol;
  for (int k0 = 0; k0 < 1024; k0 += 32) {
    uint4 a0 = *(const uint4*)(aptr + k0);
    uint4 a1 = *(const uint4*)(aptr + k0 + 8);
    uint4 b0 = *(const uint4*)(bptr + k0);
    uint4 b1 = *(const uint4*)(bptr + k0 + 8);
    __syncthreads();
    *(uint4*)&As[srow * GLD + scol] = a0;
    *(uint4*)&As[srow * GLD + scol + 8] = a1;
    *(uint4*)&Bs[srow * GLD + scol] = b0;
    *(uint4*)&Bs[srow * GLD + scol + 8] = b1;
    __syncthreads();
    bf16x8 af[4], bfr[4];
#pragma unroll
    for (int mt = 0; mt < 4; ++mt)
      af[mt] = *(const bf16x8*)&As[(wm + mt * 16 + m16) * GLD + q * 8];
#pragma unroll
    for (int nt = 0; nt < 4; ++nt)
      bfr[nt] = *(const bf16x8*)&Bs[(wn + nt * 16 + m16) * GLD + q * 8];
#pragma unroll
    for (int mt = 0; mt < 4; ++mt)
#pragma unroll
      for (int nt = 0; nt < 4; ++nt)
        acc[mt][nt] = __builtin_amdgcn_mfma_f32_16x16x32_bf16(af[mt], bfr[nt], acc[mt][nt], 0, 0, 0);
  }
  int hh = (bn + wn) >> 6;   // head this wave owns (64 cols = 1 head)
  if (z == 2) {
    // ---- V: plain cast, store transposed vt[n][t]; r=0..3 are contiguous t ----
#pragma unroll
    for (int nt = 0; nt < 4; ++nt) {
      int n = bn + wn + nt * 16 + m16;
#pragma unroll
      for (int mt = 0; mt < 4; ++mt) {
        int t0 = bm + wm + mt * 16 + q * 4;
        ushort4 val;
        val.x = f2bf(acc[mt][nt][0]);
        val.y = f2bf(acc[mt][nt][1]);
        val.z = f2bf(acc[mt][nt][2]);
        val.w = f2bf(acc[mt][nt][3]);
        *(ushort4*)(vt + (size_t)n * 2048 + t0) = val;
      }
    }
  } else {
    // ---- Q/K: cosine-norm * s_eff + rotary, write bf16 [t][h*64+d] ----
    u16* dst = z ? kb : qb;
    float se0 = s_qk[hh * 64 +  0 + m16] * 32.0f;   // sqrt(1024)=32
    float se1 = s_qk[hh * 64 + 16 + m16] * 32.0f;
    float se2 = s_qk[hh * 64 + 32 + m16] * 32.0f;
    float se3 = s_qk[hh * 64 + 48 + m16] * 32.0f;
#pragma unroll
    for (int mt = 0; mt < 4; ++mt)
#pragma unroll
      for (int r = 0; r < 4; ++r) {
        float ss = acc[mt][0][r] * acc[mt][0][r] + acc[mt][1][r] * acc[mt][1][r]
                 + acc[mt][2][r] * acc[mt][2][r] + acc[mt][3][r] * acc[mt][3][r];
        ss += __shfl_xor(ss, 1); ss += __shfl_xor(ss, 2);
        ss += __shfl_xor(ss, 4); ss += __shfl_xor(ss, 8);
        float inv = rsqrtf(ss + 1e-12f);
        int t = bm + wm + mt * 16 + q * 4 + r;
        float2 cs = rtab[t * 16 + m16];
        float x0 = acc[mt][0][r] * inv * se0;
        float x1 = acc[mt][1][r] * inv * se1;
        float x2 = acc[mt][2][r] * inv * se2;
        float x3 = acc[mt][3][r] * inv * se3;
        size_t off = (size_t)t * 1024 + hh * 64 + m16;
        dst[off]      = f2bf(x0 * cs.x + x2 * cs.y);   // d<16:  x1*c + x2*s
        dst[off + 16] = f2bf(x1);                      // 16<=d<32: freq 0
        dst[off + 32] = f2bf(x2 * cs.x - x0 * cs.y);   // 32<=d<48: x2*c - x1*s
        dst[off + 48] = f2bf(x3);                      // d>=48: freq 0
      }
  }
}

// ------- bf16 MFMA GEMM 128x128, split-K=2: Cz = A[:, kh*KH:+KH] * B^T -------
// grid.z = 2*nproj; proj = z>>1 selects B matrix (stride bz); kh = z&1.
// Each z writes its own fp32 partial buffer at C + z*cz.
#define KH 512
__global__ __launch_bounds__(256) void gemm128(const u16* __restrict__ A,
                                               const u16* __restrict__ Bmat,
                                               float* __restrict__ C,
                                               int K, int N, size_t bz, size_t cz) {
  __shared__ alignas(16) u16 As[128 * GLD];
  __shared__ alignas(16) u16 Bs[128 * GLD];
  int z = blockIdx.z;
  const u16* B = Bmat + (size_t)(z >> 1) * bz;
  float* Cz = C + (size_t)z * cz;
  int kbeg = (z & 1) * KH;
  int tid = threadIdx.x;
  int bm = blockIdx.y * 128, bn = blockIdx.x * 128;
  int lane = tid & 63, w = tid >> 6;
  int wm = (w >> 1) * 64, wn = (w & 1) * 64;
  int m16 = lane & 15, q = lane >> 4;
  f32x4 acc[4][4] = {};
  int srow = tid >> 1, scol = (tid & 1) * 16;
  const u16* aptr = A + (size_t)(bm + srow) * K + scol;
  const u16* bptr = B + (size_t)(bn + srow) * K + scol;
  for (int k0 = kbeg; k0 < kbeg + KH; k0 += 32) {
    uint4 a0 = *(const uint4*)(aptr + k0);
    uint4 a1 = *(const uint4*)(aptr + k0 + 8);
    uint4 b0 = *(const uint4*)(bptr + k0);
    uint4 b1 = *(const uint4*)(bptr + k0 + 8);
    __syncthreads();
    *(uint4*)&As[srow * GLD + scol] = a0;
    *(uint4*)&As[srow * GLD + scol + 8] = a1;
    *(uint4*)&Bs[srow * GLD + scol] = b0;
    *(uint4*)&Bs[srow * GLD + scol + 8] = b1;
    __syncthreads();
    bf16x8 af[4], bfr[4];
#pragma unroll
    for (int mt = 0; mt < 4; ++mt)
      af[mt] = *(const bf16x8*)&As[(wm + mt * 16 + m16) * GLD + q * 8];
#pragma unroll
    for (int nt = 0; nt < 4; ++nt)
      bfr[nt] = *(const bf16x8*)&Bs[(wn + nt * 16 + m16) * GLD + q * 8];
#pragma unroll
    for (int mt = 0; mt < 4; ++mt)
#pragma unroll
      for (int nt = 0; nt < 4; ++nt)
        acc[mt][nt] = __builtin_amdgcn_mfma_f32_16x16x32_bf16(af[mt], bfr[nt], acc[mt][nt], 0, 0, 0);
  }
#pragma unroll
  for (int mt = 0; mt < 4; ++mt)
#pragma unroll
    for (int nt = 0; nt < 4; ++nt)
#pragma unroll
      for (int r = 0; r < 4; ++r) {
        int row = bm + wm + mt * 16 + q * 4 + r;
        int col = bn + wn + nt * 16 + m16;
        Cz[(size_t)row * N + col] = acc[mt][nt][r];
      }
}

// ---- out = p0 + p1 (o-proj split-K reduce), fp32, n div by 1024 ----
__global__ __launch_bounds__(256) void addout(const float* __restrict__ p0,
                                              const float* __restrict__ p1,
                                              float* __restrict__ out, int n) {
  int i = (blockIdx.x * 256 + threadIdx.x) * 4;
  if (i >= n) return;
  float4 a = *(const float4*)(p0 + i);
  float4 b = *(const float4*)(p1 + i);
  float4 o = {a.x + b.x, a.y + b.y, a.z + b.z, a.w + b.w};
  *(float4*)(out + i) = o;
}

// ------------- MFMA flash attention, split-key partials ----------
// grid (h=16, 32 qt, 4 chunks); block 256 (4 waves), 64 q-rows per block.
// no-rescale softmax (|score*0.12| <= 0.27): partials combine exactly as
// y = sum_c Z_c * L_c / sum_c L_c  with Z_c the per-chunk-normalized output.
#define ALD 72
__global__ __launch_bounds__(256) void attn_mfma(const u16* __restrict__ qb,
                                                 const u16* __restrict__ kb,
                                                 const u16* __restrict__ vt,
                                                 u16* __restrict__ Zp,
                                                 float* __restrict__ Lp) {
  __shared__ alignas(16) u16 Ks[64 * ALD];        // K tile [key][d]
  __shared__ alignas(16) u16 Vt[64 * ALD];        // V tile [d][key] (pre-transposed src)
  __shared__ alignas(16) u16 Ps[4 * 16 * ALD];    // per-wave P [row][key]
  int h = blockIdx.x;
  int qt = 31 - blockIdx.y;            // heavy q-tiles dispatch first
  int c = blockIdx.z;
  int w4 = (qt + 4) >> 2;              // chunk width = ceil((qt+1)/4) key-tiles
  int jb = c * w4;
  int je = min(jb + w4, qt + 1);
  int slot = (h * 32 + qt) * 4 + c;
  int t0 = qt * 64;
  int tid = threadIdx.x;
  int lane = tid & 63, w = tid >> 6;
  int m16 = lane & 15, q = lane >> 4;
  u16* zout = Zp + (size_t)slot * 4096;
  float* lout = Lp + (size_t)slot * 64;
  if (jb >= je) {                      // empty chunk: zero its slot
#pragma unroll
    for (int nt = 0; nt < 4; ++nt)
#pragma unroll
      for (int r = 0; r < 4; ++r)
        zout[(w * 16 + q * 4 + r) * 64 + nt * 16 + m16] = 0;
    if (m16 == 0)
#pragma unroll
      for (int r = 0; r < 4; ++r) lout[w * 16 + q * 4 + r] = 0.f;
    return;
  }
  const u16* qrow = qb + (size_t)(t0 + w * 16 + m16) * 1024 + h * 64;
  bf16x8 qa0 = *(const bf16x8*)(qrow + q * 8);
  bf16x8 qa1 = *(const bf16x8*)(qrow + 32 + q * 8);
  f32x4 Yacc[4] = {};
  float lsum[4] = {0.f, 0.f, 0.f, 0.f};
  int trow = t0 + w * 16 + q * 4;
  int krow_s = tid >> 2, kcol_s = (tid & 3) * 16;   // K staging: 4 thr/row
  int vd_s = tid >> 2, vk_s = (tid & 3) * 16;       // V staging: [d][key] rows
  u16* pw = &Ps[w * 16 * ALD];
  for (int jt = jb; jt < je; ++jt) {
    int j0 = jt * 64;
    const u16* ksrc = kb + (size_t)(j0 + krow_s) * 1024 + h * 64 + kcol_s;
    uint4 kv0 = *(const uint4*)ksrc;
    uint4 kv1 = *(const uint4*)(ksrc + 8);
    const u16* vsrc = vt + (size_t)(h * 64 + vd_s) * 2048 + j0 + vk_s;
    uint4 vv0 = *(const uint4*)vsrc;
    uint4 vv1 = *(const uint4*)(vsrc + 8);
    __syncthreads();   // protect prev-iter LDS reads
    *(uint4*)&Ks[krow_s * ALD + kcol_s] = kv0;
    *(uint4*)&Ks[krow_s * ALD + kcol_s + 8] = kv1;
    *(uint4*)&Vt[vd_s * ALD + vk_s] = vv0;
    *(uint4*)&Vt[vd_s * ALD + vk_s + 8] = vv1;
    __syncthreads();
    // ---- scores: S[m][n] = sum_d Q[m][d] K[j0+n][d]
    f32x4 S[4] = {};
#pragma unroll
    for (int nt = 0; nt < 4; ++nt) {
      bf16x8 b0 = *(const bf16x8*)&Ks[(nt * 16 + m16) * ALD + q * 8];
      bf16x8 b1 = *(const bf16x8*)&Ks[(nt * 16 + m16) * ALD + 32 + q * 8];
      S[nt] = __builtin_amdgcn_mfma_f32_16x16x32_bf16(qa0, b0, S[nt], 0, 0, 0);
      S[nt] = __builtin_amdgcn_mfma_f32_16x16x32_bf16(qa1, b1, S[nt], 0, 0, 0);
    }
    // ---- exp + causal mask, row sums, P -> LDS
    bool diag = (jt == qt);
    float tmp[4] = {0.f, 0.f, 0.f, 0.f};
#pragma unroll
    for (int nt = 0; nt < 4; ++nt) {
      int j = j0 + nt * 16 + m16;
#pragma unroll
      for (int r = 0; r < 4; ++r) {
        float p = __expf(S[nt][r] * 0.12f);
        if (diag && (j > trow + r)) p = 0.f;
        tmp[r] += p;
        pw[(q * 4 + r) * ALD + nt * 16 + m16] = f2bf(p);
      }
    }
#pragma unroll
    for (int r = 0; r < 4; ++r) {
      float s = tmp[r];
      s += __shfl_xor(s, 1); s += __shfl_xor(s, 2);
      s += __shfl_xor(s, 4); s += __shfl_xor(s, 8);
      lsum[r] += s;
    }
    // ---- P C-layout -> A-layout via wave-private LDS (no barrier needed)
    bf16x8 pa0 = *(const bf16x8*)&pw[m16 * ALD + q * 8];
    bf16x8 pa1 = *(const bf16x8*)&pw[m16 * ALD + 32 + q * 8];
    // ---- PV: Y[m][d] += sum_k P[m][k] V[k][d]
#pragma unroll
    for (int nt = 0; nt < 4; ++nt) {
      bf16x8 b0 = *(const bf16x8*)&Vt[(nt * 16 + m16) * ALD + q * 8];
      bf16x8 b1 = *(const bf16x8*)&Vt[(nt * 16 + m16) * ALD + 32 + q * 8];
      Yacc[nt] = __builtin_amdgcn_mfma_f32_16x16x32_bf16(pa0, b0, Yacc[nt], 0, 0, 0);
      Yacc[nt] = __builtin_amdgcn_mfma_f32_16x16x32_bf16(pa1, b1, Yacc[nt], 0, 0, 0);
    }
  }
  // ---- epilogue: Z = Y / L (per-chunk normalized), store Z bf16 + L fp32
#pragma unroll
  for (int r = 0; r < 4; ++r) {
    float inv = __builtin_amdgcn_rcpf(lsum[r]);
#pragma unroll
    for (int nt = 0; nt < 4; ++nt)
      zout[(w * 16 + q * 4 + r) * 64 + nt * 16 + m16] = f2bf(Yacc[nt][r] * inv);
  }
  if (m16 == 0)
#pragma unroll
    for (int r = 0; r < 4; ++r) lout[w * 16 + q * 4 + r] = lsum[r];
}

// ------- combine partials: yb[t][h*64+d] = sum_c Z*L / sum_c L -------
__global__ __launch_bounds__(256) void combine(const u16* __restrict__ Zp,
                                               const float* __restrict__ Lp,
                                               u16* __restrict__ yb) {
  int tid = threadIdx.x;
  int g = blockIdx.x * 4 + (tid >> 6);   // row id: h*2048 + t
  int d = tid & 63;
  int h = g >> 11, t = g & 2047;
  int qt = t >> 6, r = t & 63;
  int base = (h * 32 + qt) * 4;
  float acc = 0.f, lt = 0.f;
#pragma unroll
  for (int c = 0; c < 4; ++c) {
    float L = Lp[(size_t)(base + c) * 64 + r];
    float z = bf2f(Zp[(size_t)(base + c) * 4096 + r * 64 + d]);
    acc += z * L;
    lt += L;
  }
  yb[(size_t)t * 1024 + h * 64 + d] = f2bf(acc / lt);
}

extern "C" void kernel_launch(void* const* d_in, const int* in_sizes, int n_in,
                              void* d_out, int out_size, void* d_ws, size_t ws_size,
                              hipStream_t stream) {
  const float* x   = (const float*)d_in[0];
  const float* Wq  = (const float*)d_in[1];
  const float* Wk  = (const float*)d_in[2];
  const float* Wv  = (const float*)d_in[3];
  const float* Wo  = (const float*)d_in[4];
  const float* sqk = (const float*)d_in[5];
  float* out = (float*)d_out;
  char* ws = (char*)d_ws;

  // workspace layout (non-overlapping):
  //   0-  4 : xb bf16 x
  //   4- 12 : Wt 4x bf16 [n][k]
  //  12-12.25: rtab (float2[2048*16] = 256 KB)
  //  16- 20 : qb16
  //  20- 24 : kb16
  //  24- 28 : vt16
  //  28- 44 : Zp (bf16 partials)
  //  44- 45 : Lp
  //  45- 49 : yb
  //  49- 65 : o-proj split-K fp32 partials, 2 x 8MB
  u16*    xb   = (u16*)ws;
  u16*    Wt   = (u16*)(ws + ((size_t)4 << 20));
  float2* rtab = (float2*)(ws + ((size_t)12 << 20));
  u16*    qb16 = (u16*)(ws + ((size_t)16 << 20));
  u16*    kb16 = (u16*)(ws + ((size_t)20 << 20));
  u16*    vt16 = (u16*)(ws + ((size_t)24 << 20));
  u16*    Zp   = (u16*)(ws + ((size_t)28 << 20));
  float*  Lp   = (float*)(ws + ((size_t)44 << 20));
  u16*    yb   = (u16*)(ws + ((size_t)45 << 20));
  float*  op   = (float*)(ws + ((size_t)49 << 20));
  u16*    Wto  = Wt + (size_t)3 * 1024 * 1024;
  const size_t PSTRIDE = (size_t)2048 * 1024;        // 2M floats = 8MB

  cast_kernel<<<2048, 256, 0, stream>>>(x, xb, 2048 * 1024, rtab);
  transcast<<<dim3(16, 16, 4), 256, 0, stream>>>(Wq, Wk, Wv, Wo, Wt);
  // fused QKV: full K, norm+rope+transpose in epilogue, bf16 out
  gemm_qkv<<<dim3(8, 16, 3), 256, 0, stream>>>(xb, Wt, qb16, kb16, vt16, sqk, rtab);
  attn_mfma<<<dim3(16, 32, 4), 256, 0, stream>>>(qb16, kb16, vt16, Zp, Lp);
  combine<<<8192, 256, 0, stream>>>(Zp, Lp, yb);
  // o-proj, split-K=2: 256 blocks, then reduce
  gemm128<<<dim3(8, 16, 2), 256, 0, stream>>>(yb, Wto, op, 1024, 1024, 0, PSTRIDE);
  addout<<<2048, 256, 0, stream>>>(op, op + PSTRIDE, out, 2048 * 1024);
}

// Round 2
// 153.508 us; speedup vs baseline: 1.1589x; 1.0680x over previous
//
#include <hip/hip_runtime.h>

typedef unsigned short u16;
typedef unsigned int u32;
typedef __attribute__((ext_vector_type(8))) short bf16x8;
typedef __attribute__((ext_vector_type(4))) float f32x4;

__device__ __forceinline__ u16 f2bf(float x) {
  unsigned u = __float_as_uint(x);
  u += 0x7fffu + ((u >> 16) & 1u);   // RNE
  return (u16)(u >> 16);
}
__device__ __forceinline__ float bf2f(u16 z) {
  return __uint_as_float((u32)z << 16);
}

// ---- cast fp32 -> bf16 (RNE); n divisible by 1024. Also builds rope table ----
// rtab[t*16+i] = {cos(t*fr_i), sin(t*fr_i)}, fr_i = 1024^(-i/15), t<2048, i<16.
__global__ __launch_bounds__(256) void cast_kernel(const float* __restrict__ in,
                                                   u16* __restrict__ out, int n,
                                                   float2* __restrict__ rtab) {
  int g = blockIdx.x * 256 + threadIdx.x;
  int i = g * 4;
  if (i < n) {
    float4 f = *(const float4*)(in + i);
    ushort4 o;
    o.x = f2bf(f.x); o.y = f2bf(f.y); o.z = f2bf(f.z); o.w = f2bf(f.w);
    *(ushort4*)(out + i) = o;
  }
  if (g < 2048 * 16) {
    int t = g >> 4, ii = g & 15;
    float fr = exp2f(-10.0f * (float)ii / 15.0f);
    float th = (float)t * fr;
    rtab[g] = make_float2(cosf(th), sinf(th));
  }
}

// ------------- transpose+cast 4 weights: W[k][n] fp32 -> Wt[n][k] bf16 -------------
__global__ __launch_bounds__(256) void transcast(const float* __restrict__ W0,
                                                 const float* __restrict__ W1,
                                                 const float* __restrict__ W2,
                                                 const float* __restrict__ W3,
                                                 u16* __restrict__ out) {
  __shared__ alignas(16) u16 ls[64 * 72];
  int z = blockIdx.z;
  const float* W = (z == 0) ? W0 : (z == 1) ? W1 : (z == 2) ? W2 : W3;
  u16* o = out + (size_t)z * (1024u * 1024u);
  int kt = blockIdx.y * 64, nt = blockIdx.x * 64;
  int tid = threadIdx.x;
  int r = tid >> 2, c0 = (tid & 3) * 16;
  const float* src = W + (size_t)(kt + r) * 1024 + nt + c0;
  u16 tmp[16];
#pragma unroll
  for (int c = 0; c < 16; c += 4) {
    float4 f = *(const float4*)(src + c);
    tmp[c + 0] = f2bf(f.x); tmp[c + 1] = f2bf(f.y);
    tmp[c + 2] = f2bf(f.z); tmp[c + 3] = f2bf(f.w);
  }
#pragma unroll
  for (int c = 0; c < 16; ++c) ls[r * 72 + c0 + c] = tmp[c];
  __syncthreads();
#pragma unroll
  for (int pass = 0; pass < 4; ++pass) {
    int n = pass * 16 + (tid >> 4);
    int kk = (tid & 15) * 4;
    ushort4 val;
    val.x = ls[(kk + 0) * 72 + n];
    val.y = ls[(kk + 1) * 72 + n];
    val.z = ls[(kk + 2) * 72 + n];
    val.w = ls[(kk + 3) * 72 + n];
    *(ushort4*)(o + (size_t)(nt + n) * 1024 + kt + kk) = val;
  }
}

#define GLD 40  // LDS stride: rows alias at +8 -> 2-way on banks (free)

// ---- fused QKV GEMM 128x128, full K=1024, epilogue norm+rope (q,k) / transpose (v) ----
// grid (8 n-tiles, 16 m-tiles, z=3 projections). A wave's 64 cols = one full head,
// so cosine-norm (shfl over m16 + sum over nt) and rotary (nt <-> nt^2 pairing)
// are wave/register-local. V is written transposed via per-lane ushort4 (r = t run).
// Register prefetch of next k-tile hides global latency (1.5 blocks/CU).
__global__ __launch_bounds__(256) void gemm_qkv(const u16* __restrict__ A,
                                                const u16* __restrict__ Wt,
                                                u16* __restrict__ qb,
                                                u16* __restrict__ kb,
                                                u16* __restrict__ vt,
                                                const float* __restrict__ s_qk,
                                                const float2* __restrict__ rtab) {
  __shared__ alignas(16) u16 As[128 * GLD];
  __shared__ alignas(16) u16 Bs[128 * GLD];
  int z = blockIdx.z;
  const u16* B = Wt + (size_t)z * (1024u * 1024u);
  int tid = threadIdx.x;
  int bm = blockIdx.y * 128, bn = blockIdx.x * 128;
  int lane = tid & 63, w = tid >> 6;
  int wm = (w >> 1) * 64, wn = (w & 1) * 64;
  int m16 = lane & 15, q = lane >> 4;
  f32x4 acc[4][4] = {};
  int srow = tid >> 1, scol = (tid & 1) * 16;
  const u16* aptr = A + (size_t)(bm + srow) * 1024 + scol;
  const u16* bptr = B + (size_t)(bn + srow) * 1024 + scol;
  uint4 a0 = *(const uint4*)(aptr);
  uint4 a1 = *(const uint4*)(aptr + 8);
  uint4 b0 = *(const uint4*)(bptr);
  uint4 b1 = *(const uint4*)(bptr + 8);
  for (int k0 = 0; k0 < 1024; k0 += 32) {
    __syncthreads();
    *(uint4*)&As[srow * GLD + scol] = a0;
    *(uint4*)&As[srow * GLD + scol + 8] = a1;
    *(uint4*)&Bs[srow * GLD + scol] = b0;
    *(uint4*)&Bs[srow * GLD + scol + 8] = b1;
    uint4 na0, na1, nb0, nb1;
    if (k0 < 992) {   // issue next-tile loads early; land during compute
      na0 = *(const uint4*)(aptr + k0 + 32);
      na1 = *(const uint4*)(aptr + k0 + 40);
      nb0 = *(const uint4*)(bptr + k0 + 32);
      nb1 = *(const uint4*)(bptr + k0 + 40);
    }
    __syncthreads();
    bf16x8 af[4], bfr[4];
#pragma unroll
    for (int mt = 0; mt < 4; ++mt)
      af[mt] = *(const bf16x8*)&As[(wm + mt * 16 + m16) * GLD + q * 8];
#pragma unroll
    for (int nt = 0; nt < 4; ++nt)
      bfr[nt] = *(const bf16x8*)&Bs[(wn + nt * 16 + m16) * GLD + q * 8];
#pragma unroll
    for (int mt = 0; mt < 4; ++mt)
#pragma unroll
      for (int nt = 0; nt < 4; ++nt)
        acc[mt][nt] = __builtin_amdgcn_mfma_f32_16x16x32_bf16(af[mt], bfr[nt], acc[mt][nt], 0, 0, 0);
    if (k0 < 992) { a0 = na0; a1 = na1; b0 = nb0; b1 = nb1; }
  }
  int hh = (bn + wn) >> 6;   // head this wave owns (64 cols = 1 head)
  if (z == 2) {
    // ---- V: plain cast, store transposed vt[n][t]; r=0..3 are contiguous t ----
#pragma unroll
    for (int nt = 0; nt < 4; ++nt) {
      int n = bn + wn + nt * 16 + m16;
#pragma unroll
      for (int mt = 0; mt < 4; ++mt) {
        int t0 = bm + wm + mt * 16 + q * 4;
        ushort4 val;
        val.x = f2bf(acc[mt][nt][0]);
        val.y = f2bf(acc[mt][nt][1]);
        val.z = f2bf(acc[mt][nt][2]);
        val.w = f2bf(acc[mt][nt][3]);
        *(ushort4*)(vt + (size_t)n * 2048 + t0) = val;
      }
    }
  } else {
    // ---- Q/K: cosine-norm * s_eff + rotary, write bf16 [t][h*64+d] ----
    u16* dst = z ? kb : qb;
    float se0 = s_qk[hh * 64 +  0 + m16] * 32.0f;   // sqrt(1024)=32
    float se1 = s_qk[hh * 64 + 16 + m16] * 32.0f;
    float se2 = s_qk[hh * 64 + 32 + m16] * 32.0f;
    float se3 = s_qk[hh * 64 + 48 + m16] * 32.0f;
#pragma unroll
    for (int mt = 0; mt < 4; ++mt)
#pragma unroll
      for (int r = 0; r < 4; ++r) {
        float ss = acc[mt][0][r] * acc[mt][0][r] + acc[mt][1][r] * acc[mt][1][r]
                 + acc[mt][2][r] * acc[mt][2][r] + acc[mt][3][r] * acc[mt][3][r];
        ss += __shfl_xor(ss, 1); ss += __shfl_xor(ss, 2);
        ss += __shfl_xor(ss, 4); ss += __shfl_xor(ss, 8);
        float inv = rsqrtf(ss + 1e-12f);
        int t = bm + wm + mt * 16 + q * 4 + r;
        float2 cs = rtab[t * 16 + m16];
        float x0 = acc[mt][0][r] * inv * se0;
        float x1 = acc[mt][1][r] * inv * se1;
        float x2 = acc[mt][2][r] * inv * se2;
        float x3 = acc[mt][3][r] * inv * se3;
        size_t off = (size_t)t * 1024 + hh * 64 + m16;
        dst[off]      = f2bf(x0 * cs.x + x2 * cs.y);   // d<16:  x1*c + x2*s
        dst[off + 16] = f2bf(x1);                      // 16<=d<32: freq 0
        dst[off + 32] = f2bf(x2 * cs.x - x0 * cs.y);   // 32<=d<48: x2*c - x1*s
        dst[off + 48] = f2bf(x3);                      // d>=48: freq 0
      }
  }
}

// ------------- MFMA flash attention, folded-triangle, no partials ----------
// grid (h=16, y=16); block 256 (4 waves), 64 q-rows per q-tile.
// Block (h,y) does q-tiles 31-y then y: (32-y)+(y+1) = 33 key-tile iters for
// EVERY block -> uniform work, 1 block/CU, no Zp/Lp partials, no combine.
// no-rescale softmax (|score*0.12| <= 0.27): single L per row, Y/L at end.
// K/V tile for jt+1 is register-prefetched during jt's compute (T14).
#define ALD 72
__global__ __launch_bounds__(256) void attn_fold(const u16* __restrict__ qb,
                                                 const u16* __restrict__ kb,
                                                 const u16* __restrict__ vt,
                                                 u16* __restrict__ yb) {
  __shared__ alignas(16) u16 Ks[64 * ALD];        // K tile [key][d]
  __shared__ alignas(16) u16 Vt[64 * ALD];        // V tile [d][key] (pre-transposed src)
  __shared__ alignas(16) u16 Ps[4 * 16 * ALD];    // per-wave P [row][key]
  int h = blockIdx.x;
  int y = blockIdx.y;
  int tid = threadIdx.x;
  int lane = tid & 63, w = tid >> 6;
  int m16 = lane & 15, q = lane >> 4;
  int krow_s = tid >> 2, kcol_s = (tid & 3) * 16;   // staging: 4 thr/row, 2 uint4 each
  const u16* kbase = kb + (size_t)krow_s * 1024 + h * 64 + kcol_s;
  const u16* vbase = vt + (size_t)(h * 64 + krow_s) * 2048 + kcol_s;
  u16* pw = &Ps[w * 16 * ALD];
#pragma unroll 1
  for (int half = 0; half < 2; ++half) {
    int qt = half ? y : 31 - y;
    int t0 = qt * 64;
    const u16* qrow = qb + (size_t)(t0 + w * 16 + m16) * 1024 + h * 64;
    bf16x8 qa0 = *(const bf16x8*)(qrow + q * 8);
    bf16x8 qa1 = *(const bf16x8*)(qrow + 32 + q * 8);
    f32x4 Yacc[4] = {};
    float lsum[4] = {0.f, 0.f, 0.f, 0.f};
    int trow = t0 + w * 16 + q * 4;
    uint4 kv0 = *(const uint4*)kbase;
    uint4 kv1 = *(const uint4*)(kbase + 8);
    uint4 vv0 = *(const uint4*)vbase;
    uint4 vv1 = *(const uint4*)(vbase + 8);
    for (int jt = 0; jt <= qt; ++jt) {
      __syncthreads();   // prev-iter (or prev-half) LDS reads complete
      *(uint4*)&Ks[krow_s * ALD + kcol_s] = kv0;
      *(uint4*)&Ks[krow_s * ALD + kcol_s + 8] = kv1;
      *(uint4*)&Vt[krow_s * ALD + kcol_s] = vv0;
      *(uint4*)&Vt[krow_s * ALD + kcol_s + 8] = vv1;
      uint4 kn0, kn1, vn0, vn1;
      if (jt < qt) {   // issue next-tile loads early; land during compute
        const u16* kp = kbase + (size_t)(jt + 1) * 65536;   // 64 rows * 1024
        const u16* vp = vbase + (jt + 1) * 64;
        kn0 = *(const uint4*)kp;
        kn1 = *(const uint4*)(kp + 8);
        vn0 = *(const uint4*)vp;
        vn1 = *(const uint4*)(vp + 8);
      }
      __syncthreads();
      // ---- scores: S[m][n] = sum_d Q[m][d] K[j0+n][d]
      f32x4 S[4] = {};
#pragma unroll
      for (int nt = 0; nt < 4; ++nt) {
        bf16x8 b0 = *(const bf16x8*)&Ks[(nt * 16 + m16) * ALD + q * 8];
        bf16x8 b1 = *(const bf16x8*)&Ks[(nt * 16 + m16) * ALD + 32 + q * 8];
        S[nt] = __builtin_amdgcn_mfma_f32_16x16x32_bf16(qa0, b0, S[nt], 0, 0, 0);
        S[nt] = __builtin_amdgcn_mfma_f32_16x16x32_bf16(qa1, b1, S[nt], 0, 0, 0);
      }
      // ---- exp + causal mask, row sums, P -> LDS
      bool diag = (jt == qt);
      int j0 = jt * 64;
      float tmp[4] = {0.f, 0.f, 0.f, 0.f};
#pragma unroll
      for (int nt = 0; nt < 4; ++nt) {
        int j = j0 + nt * 16 + m16;
#pragma unroll
        for (int r = 0; r < 4; ++r) {
          // exp(S*0.12) = exp2(S * 0.12*log2(e))
          float p = __builtin_amdgcn_exp2f(S[nt][r] * 0.17312340490667562f);
          if (diag && (j > trow + r)) p = 0.f;
          tmp[r] += p;
          pw[(q * 4 + r) * ALD + nt * 16 + m16] = f2bf(p);
        }
      }
#pragma unroll
      for (int r = 0; r < 4; ++r) {
        float s = tmp[r];
        s += __shfl_xor(s, 1); s += __shfl_xor(s, 2);
        s += __shfl_xor(s, 4); s += __shfl_xor(s, 8);
        lsum[r] += s;
      }
      // ---- P C-layout -> A-layout via wave-private LDS (no barrier needed)
      bf16x8 pa0 = *(const bf16x8*)&pw[m16 * ALD + q * 8];
      bf16x8 pa1 = *(const bf16x8*)&pw[m16 * ALD + 32 + q * 8];
      // ---- PV: Y[m][d] += sum_k P[m][k] V[k][d]
#pragma unroll
      for (int nt = 0; nt < 4; ++nt) {
        bf16x8 b0 = *(const bf16x8*)&Vt[(nt * 16 + m16) * ALD + q * 8];
        bf16x8 b1 = *(const bf16x8*)&Vt[(nt * 16 + m16) * ALD + 32 + q * 8];
        Yacc[nt] = __builtin_amdgcn_mfma_f32_16x16x32_bf16(pa0, b0, Yacc[nt], 0, 0, 0);
        Yacc[nt] = __builtin_amdgcn_mfma_f32_16x16x32_bf16(pa1, b1, Yacc[nt], 0, 0, 0);
      }
      if (jt < qt) { kv0 = kn0; kv1 = kn1; vv0 = vn0; vv1 = vn1; }
    }
    // ---- epilogue: yb[t][h*64+d] = Y/L, bf16
#pragma unroll
    for (int r = 0; r < 4; ++r) {
      float inv = __builtin_amdgcn_rcpf(lsum[r]);
      int t = t0 + w * 16 + q * 4 + r;
#pragma unroll
      for (int nt = 0; nt < 4; ++nt)
        yb[(size_t)t * 1024 + h * 64 + nt * 16 + m16] = f2bf(Yacc[nt][r] * inv);
    }
  }
}

// ------- o-proj GEMM: out[2048][1024] fp32 = yb bf16 @ Wto^T, full K ------
// 128M x 64N tiles -> grid (16,16) = 256 blocks (1/CU). Wave w: rows w*32..+31,
// all 64 cols. Register prefetch covers 1-block/CU load latency.
__global__ __launch_bounds__(256) void gemm_o(const u16* __restrict__ A,
                                              const u16* __restrict__ B,
                                              float* __restrict__ C) {
  __shared__ alignas(16) u16 As[128 * GLD];
  __shared__ alignas(16) u16 Bs[64 * GLD];
  int tid = threadIdx.x;
  int bm = blockIdx.y * 128, bn = blockIdx.x * 64;
  int lane = tid & 63, w = tid >> 6;
  int wm = w * 32;
  int m16 = lane & 15, q = lane >> 4;
  f32x4 acc[2][4] = {};
  int srA = tid >> 1, scA = (tid & 1) * 16;
  int srB = tid >> 2, scB = (tid & 3) * 8;
  const u16* aptr = A + (size_t)(bm + srA) * 1024 + scA;
  const u16* bptr = B + (size_t)(bn + srB) * 1024 + scB;
  uint4 a0 = *(const uint4*)(aptr);
  uint4 a1 = *(const uint4*)(aptr + 8);
  uint4 b0 = *(const uint4*)(bptr);
  for (int k0 = 0; k0 < 1024; k0 += 32) {
    __syncthreads();
    *(uint4*)&As[srA * GLD + scA] = a0;
    *(uint4*)&As[srA * GLD + scA + 8] = a1;
    *(uint4*)&Bs[srB * GLD + scB] = b0;
    uint4 na0, na1, nb0;
    if (k0 < 992) {
      na0 = *(const uint4*)(aptr + k0 + 32);
      na1 = *(const uint4*)(aptr + k0 + 40);
      nb0 = *(const uint4*)(bptr + k0 + 32);
    }
    __syncthreads();
    bf16x8 af[2], bfr[4];
#pragma unroll
    for (int mt = 0; mt < 2; ++mt)
      af[mt] = *(const bf16x8*)&As[(wm + mt * 16 + m16) * GLD + q * 8];
#pragma unroll
    for (int nt = 0; nt < 4; ++nt)
      bfr[nt] = *(const bf16x8*)&Bs[(nt * 16 + m16) * GLD + q * 8];
#pragma unroll
    for (int mt = 0; mt < 2; ++mt)
#pragma unroll
      for (int nt = 0; nt < 4; ++nt)
        acc[mt][nt] = __builtin_amdgcn_mfma_f32_16x16x32_bf16(af[mt], bfr[nt], acc[mt][nt], 0, 0, 0);
    if (k0 < 992) { a0 = na0; a1 = na1; b0 = nb0; }
  }
#pragma unroll
  for (int mt = 0; mt < 2; ++mt)
#pragma unroll
    for (int nt = 0; nt < 4; ++nt)
#pragma unroll
      for (int r = 0; r < 4; ++r) {
        int row = bm + wm + mt * 16 + q * 4 + r;
        int col = bn + nt * 16 + m16;
        C[(size_t)row * 1024 + col] = acc[mt][nt][r];
      }
}

extern "C" void kernel_launch(void* const* d_in, const int* in_sizes, int n_in,
                              void* d_out, int out_size, void* d_ws, size_t ws_size,
                              hipStream_t stream) {
  const float* x   = (const float*)d_in[0];
  const float* Wq  = (const float*)d_in[1];
  const float* Wk  = (const float*)d_in[2];
  const float* Wv  = (const float*)d_in[3];
  const float* Wo  = (const float*)d_in[4];
  const float* sqk = (const float*)d_in[5];
  float* out = (float*)d_out;
  char* ws = (char*)d_ws;

  // workspace layout (non-overlapping):
  //   0-  4 : xb bf16 x
  //   4- 12 : Wt 4x bf16 [n][k]
  //  12-12.25: rtab (float2[2048*16] = 256 KB)
  //  16- 20 : qb16
  //  20- 24 : kb16
  //  24- 28 : vt16
  //  28- 32 : yb
  u16*    xb   = (u16*)ws;
  u16*    Wt   = (u16*)(ws + ((size_t)4 << 20));
  float2* rtab = (float2*)(ws + ((size_t)12 << 20));
  u16*    qb16 = (u16*)(ws + ((size_t)16 << 20));
  u16*    kb16 = (u16*)(ws + ((size_t)20 << 20));
  u16*    vt16 = (u16*)(ws + ((size_t)24 << 20));
  u16*    yb   = (u16*)(ws + ((size_t)28 << 20));
  u16*    Wto  = Wt + (size_t)3 * 1024 * 1024;

  cast_kernel<<<2048, 256, 0, stream>>>(x, xb, 2048 * 1024, rtab);
  transcast<<<dim3(16, 16, 4), 256, 0, stream>>>(Wq, Wk, Wv, Wo, Wt);
  // fused QKV: full K, norm+rope+transpose in epilogue, bf16 out
  gemm_qkv<<<dim3(8, 16, 3), 256, 0, stream>>>(xb, Wt, qb16, kb16, vt16, sqk, rtab);
  // folded-triangle flash attention, writes yb directly
  attn_fold<<<dim3(16, 16), 256, 0, stream>>>(qb16, kb16, vt16, yb);
  // o-proj, full K, direct fp32 output
  gemm_o<<<dim3(16, 16), 256, 0, stream>>>(yb, Wto, out);
}